// Round 5
// baseline (1357.905 us; speedup 1.0000x reference)
//
#include <hip/hip_runtime.h>
#include <hip/hip_bf16.h>

#define TT 1024
#define FF 256

// ===== ATTRIBUTION ROUND: in-kernel amplification multipliers ==============
// Each kernel repeats its (idempotent) body N times so its dispatch exceeds
// the harness's 158us fill kernels and surfaces in rocprof's top-5 with its
// own counters.  True T_i = shown_dur / N (upper bound: reps may be cache-
// warm).  Remove for R5.
#define REP_LN     16
#define REP_PROJ   12
#define REP_BTERM   4
#define REP_ATTN    9
#define REP_OPROJ  28
// ===========================================================================

typedef float  f4v  __attribute__((ext_vector_type(4)));
typedef float  f16v __attribute__((ext_vector_type(16)));
typedef __bf16 bf8v __attribute__((ext_vector_type(8)));
typedef unsigned short us8v __attribute__((ext_vector_type(8)));
typedef unsigned short us4v __attribute__((ext_vector_type(4)));

static __device__ __forceinline__ unsigned short f2bf(float x) {
    return __builtin_bit_cast(unsigned short, (__bf16)x);
}
static __device__ __forceinline__ float bf2f(unsigned short u) {
    return (float)__builtin_bit_cast(__bf16, u);
}
static __device__ __forceinline__ bf8v us2bf(us8v v) {
    return __builtin_bit_cast(bf8v, v);
}

// ---------------------------------------------------------------------------
// K0: weight prep — W[k][n] fp32 -> Wt[n][k] bf16, 4 matrices (Q,K,V,O).
// (not amplified: trivially small)
// ---------------------------------------------------------------------------
__global__ __launch_bounds__(256) void k_wprep(
    const float* __restrict__ Wq, const float* __restrict__ Wk,
    const float* __restrict__ Wv, const float* __restrict__ Wo,
    unsigned short* __restrict__ Wt)
{
    __shared__ unsigned short T[32][36];
    const float* W = (blockIdx.y == 0) ? Wq : (blockIdx.y == 1) ? Wk
                   : (blockIdx.y == 2) ? Wv : Wo;
    unsigned short* dst = Wt + (blockIdx.y << 16);
    const int kt = (blockIdx.x >> 3) << 5, nt = (blockIdx.x & 7) << 5;
    const int r = threadIdx.x >> 3, c0 = (threadIdx.x & 7) << 2;
    const f4v w = *(const f4v*)&W[(kt + r) * FF + nt + c0];
    #pragma unroll
    for (int j = 0; j < 4; ++j) T[c0 + j][r] = f2bf(w[j]);
    __syncthreads();
    *(us4v*)&dst[(nt + r) * FF + kt + c0] = *(const us4v*)&T[r][c0];
}

// ---------------------------------------------------------------------------
// K1: LayerNorm(x) -> xn_bf16 ; cast q_in -> bf16.   [amplified xREP_LN]
// ---------------------------------------------------------------------------
__global__ __launch_bounds__(256) void k_ln(
    const float* __restrict__ x, const float* __restrict__ qin,
    const float* __restrict__ lng, const float* __restrict__ lnb,
    unsigned short* __restrict__ xn_bf, unsigned short* __restrict__ qin_bf)
{
    const int tid = threadIdx.x, lane = tid & 63, wv = tid >> 6;
    const int r0 = blockIdx.x << 4;

    for (int rep = 0; rep < REP_LN; ++rep) {
        #pragma unroll
        for (int u = 0; u < 4; ++u) {
            const int i4 = ((u << 8) + tid) << 2;
            const int r = i4 >> 8, c = i4 & 255;
            const f4v qv = *(const f4v*)&qin[(r0 + r) * FF + c];
            us4v o;
            #pragma unroll
            for (int j = 0; j < 4; ++j) o[j] = f2bf(qv[j]);
            *(us4v*)&qin_bf[(r0 + r) * FF + c] = o;
        }

        #pragma unroll
        for (int rr = 0; rr < 4; ++rr) {
            const int row = r0 + (wv << 2) + rr;
            float v[4], s = 0.f, s2 = 0.f;
            #pragma unroll
            for (int c4 = 0; c4 < 4; ++c4) {
                v[c4] = x[row * FF + (c4 << 6) + lane];
                s += v[c4]; s2 += v[c4] * v[c4];
            }
            #pragma unroll
            for (int off = 1; off < 64; off <<= 1) {
                s  += __shfl_xor(s, off);
                s2 += __shfl_xor(s2, off);
            }
            const float mu  = s * (1.f / FF);
            const float rsd = rsqrtf(s2 * (1.f / FF) - mu * mu + 1e-5f);
            #pragma unroll
            for (int c4 = 0; c4 < 4; ++c4) {
                const int c = (c4 << 6) + lane;
                xn_bf[row * FF + c] = f2bf((v[c4] - mu) * rsd * lng[c] + lnb[c]);
            }
        }
        __asm__ volatile("" ::: "memory");   // defeat cross-rep CSE/LICM
    }
}

// ---------------------------------------------------------------------------
// K2: MFMA projections.  z=0: Qh = (qin@Wq + bq)*0.125; z=1: Kh = xn@Wk + bk;
// z=2: Vt = (xn@Wv + bv)^T stored [bh][d][t].   [amplified xREP_PROJ]
// ---------------------------------------------------------------------------
__global__ __launch_bounds__(256) void k_proj(
    const unsigned short* __restrict__ qin_bf, const unsigned short* __restrict__ xn_bf,
    const unsigned short* __restrict__ Wt,
    const float* __restrict__ bq, const float* __restrict__ bk, const float* __restrict__ bv,
    unsigned short* __restrict__ Qh, unsigned short* __restrict__ Kh,
    unsigned short* __restrict__ Vt)
{
    __shared__ __align__(16) unsigned short As[64 * 264];
    const int z = blockIdx.y;
    const unsigned short* A = (z == 0) ? qin_bf : xn_bf;
    const unsigned short* W = Wt + (z << 16);
    const float* bias = (z == 0) ? bq : (z == 1) ? bk : bv;
    unsigned short* dst = (z == 0) ? Qh : (z == 1) ? Kh : Vt;
    const int tid = threadIdx.x;
    const int m0 = blockIdx.x << 6;

    for (int rep = 0; rep < REP_PROJ; ++rep) {
        #pragma unroll
        for (int u = 0; u < 8; ++u) {
            const int idx = (u << 8) + tid;
            const int r = idx >> 5, c = (idx & 31) << 3;
            *(us8v*)&As[r * 264 + c] = *(const us8v*)&A[(m0 + r) * FF + c];
        }
        __syncthreads();

        const int lane = tid & 63, nw = tid >> 6, gq = lane >> 5, l31 = lane & 31;
        f16v acc[2][2];
        #pragma unroll
        for (int i = 0; i < 2; ++i)
            #pragma unroll
            for (int j = 0; j < 2; ++j)
                #pragma unroll
                for (int e = 0; e < 16; ++e) acc[i][j][e] = 0.f;

        for (int ks = 0; ks < 16; ++ks) {
            const int k0 = (ks << 4) + (gq << 3);
            bf8v af[2], wf[2];
            af[0] = us2bf(*(const us8v*)&As[l31 * 264 + k0]);
            af[1] = us2bf(*(const us8v*)&As[(32 + l31) * 264 + k0]);
            wf[0] = us2bf(*(const us8v*)&W[((nw << 6) + l31) * FF + k0]);
            wf[1] = us2bf(*(const us8v*)&W[((nw << 6) + 32 + l31) * FF + k0]);
            if (z == 2) {
                #pragma unroll
                for (int ti = 0; ti < 2; ++ti)
                    #pragma unroll
                    for (int tj = 0; tj < 2; ++tj)
                        acc[ti][tj] = __builtin_amdgcn_mfma_f32_32x32x16_bf16(
                            wf[tj], af[ti], acc[ti][tj], 0, 0, 0);
            } else {
                #pragma unroll
                for (int ti = 0; ti < 2; ++ti)
                    #pragma unroll
                    for (int tj = 0; tj < 2; ++tj)
                        acc[ti][tj] = __builtin_amdgcn_mfma_f32_32x32x16_bf16(
                            af[ti], wf[tj], acc[ti][tj], 0, 0, 0);
            }
        }

        if (z != 2) {
            #pragma unroll
            for (int ti = 0; ti < 2; ++ti)
                #pragma unroll
                for (int tj = 0; tj < 2; ++tj)
                    #pragma unroll
                    for (int reg = 0; reg < 16; ++reg) {
                        const int row = (reg & 3) + ((reg >> 2) << 3) + (gq << 2);
                        const int tg = m0 + (ti << 5) + row;
                        const int n = (nw << 6) + (tj << 5) + l31;
                        float val = acc[ti][tj][reg] + bias[n];
                        if (z == 0) val *= 0.125f;
                        const int b = tg >> 10, t = tg & 1023;
                        dst[(((b << 2) + nw) << 16) + (t << 6) + (tj << 5) + l31] = f2bf(val);
                    }
        } else {
            #pragma unroll
            for (int ti = 0; ti < 2; ++ti)
                #pragma unroll
                for (int tj = 0; tj < 2; ++tj)
                    #pragma unroll
                    for (int reg = 0; reg < 16; ++reg) {
                        const int row = (reg & 3) + ((reg >> 2) << 3) + (gq << 2);
                        const int d = (tj << 5) + row;
                        const int tg = m0 + (ti << 5) + l31;
                        const float val = acc[ti][tj][reg] + bias[(nw << 6) + d];
                        const int b = tg >> 10, t = tg & 1023;
                        dst[(((b << 2) + nw) << 16) + (d << 10) + t] = f2bf(val);
                    }
        }
        __syncthreads();                     // protect As across reps
        __asm__ volatile("" ::: "memory");
    }
}

// ---------------------------------------------------------------------------
// K3: relative-position term with mask+scale folded.  [amplified xREP_BTERM]
// Bm[bh][q][t] = mask ? Qh_scaled[bh][q].posk[q][t] : -3e38  (bf16)
// ---------------------------------------------------------------------------
__global__ __launch_bounds__(256) void k_bterm(
    const unsigned short* __restrict__ Qh, const float* __restrict__ posk,
    const int* __restrict__ mask, unsigned short* __restrict__ Bm)
{
    const int tid = threadIdx.x, lane = tid & 63, wv = tid >> 6;
    const int gq = lane >> 5, m = lane & 31;
    const int q = blockIdx.y;
    const int t = (blockIdx.x << 7) + (wv << 5) + m;

    for (int rep = 0; rep < REP_BTERM; ++rep) {
        bf8v afr[4];
        #pragma unroll
        for (int kk = 0; kk < 4; ++kk)
            afr[kk] = us2bf(*(const us8v*)&Qh[(m << 16) + (q << 6) + (kk << 4) + (gq << 3)]);

        bf8v bfr[4];
        #pragma unroll
        for (int kk = 0; kk < 4; ++kk) {
            const int d0 = (kk << 4) + (gq << 3);
            const f4v p0 = *(const f4v*)&posk[(((q << 10) + t) << 6) + d0];
            const f4v p1 = *(const f4v*)&posk[(((q << 10) + t) << 6) + d0 + 4];
            bf8v bb;
            bb[0] = (__bf16)p0[0]; bb[1] = (__bf16)p0[1];
            bb[2] = (__bf16)p0[2]; bb[3] = (__bf16)p0[3];
            bb[4] = (__bf16)p1[0]; bb[5] = (__bf16)p1[1];
            bb[6] = (__bf16)p1[2]; bb[7] = (__bf16)p1[3];
            bfr[kk] = bb;
        }

        f16v acc;
        #pragma unroll
        for (int i = 0; i < 16; ++i) acc[i] = 0.f;
        #pragma unroll
        for (int kk = 0; kk < 4; ++kk)
            acc = __builtin_amdgcn_mfma_f32_32x32x16_bf16(afr[kk], bfr[kk], acc, 0, 0, 0);

        int mk[4];
        #pragma unroll
        for (int g = 0; g < 4; ++g)   // b = 2g + gq for reg group g
            mk[g] = mask[(((g << 1) + gq) << 20) + (q << 10) + t];
        #pragma unroll
        for (int reg = 0; reg < 16; ++reg) {
            const int g = reg >> 2;
            const int bhr = (reg & 3) + (g << 3) + (gq << 2);
            const float val = mk[g] ? acc[reg] : -3.0e38f;
            Bm[(bhr << 20) + (q << 10) + t] = f2bf(val);
        }
        __asm__ volatile("" ::: "memory");
    }
}

// ---------------------------------------------------------------------------
// K4: transposed flash attention (R4 structure).  [amplified xREP_ATTN]
// ---------------------------------------------------------------------------
__global__ __launch_bounds__(256, 4) void k_attn(
    const unsigned short* __restrict__ Qh, const unsigned short* __restrict__ Kh,
    const unsigned short* __restrict__ Vt, const unsigned short* __restrict__ Bm,
    unsigned short* __restrict__ aout_bf)
{
    __shared__ __align__(16) unsigned short PsT[4][16 * 132]; // per-wave [q][t]
    __shared__ __align__(16) float OLDS[2][16 * 68];          // [qg][q][d]
    __shared__ float MLDS[2][2][16];                          // [qg][{m,l}][q]

    const int tid = threadIdx.x, lane = tid & 63, wv = tid >> 6;
    const int l15 = lane & 15, quad = lane >> 4;
    const int qg = wv & 1, th = wv >> 1;
    const int blk = blockIdx.x;
    const int bh = ((blk & 7) << 2) | ((blk >> 3) & 3);  // XCD swizzle
    const int qt = blk >> 5;
    const int b = bh >> 2, h = bh & 3;
    const int q0w = (qt << 5) + (qg << 4);               // wave's 16 q rows

    for (int rep = 0; rep < REP_ATTN; ++rep) {
        bf8v qb0, qb1;
        {
            const int base = (bh << 16) + ((q0w + l15) << 6) + (quad << 3);
            qb0 = us2bf(*(const us8v*)&Qh[base]);
            qb1 = us2bf(*(const us8v*)&Qh[base + 32]);
        }

        f4v O[4];
        #pragma unroll
        for (int i = 0; i < 4; ++i) { O[i][0]=0.f; O[i][1]=0.f; O[i][2]=0.f; O[i][3]=0.f; }
        float m_run = -3.0e38f, l_run = 0.f;

        for (int cc = 0; cc < 4; ++cc) {
            const int t0c = (th << 9) + (cc << 7);   // this wave's 128-t chunk

            f4v s[8];
            #pragma unroll
            for (int nf = 0; nf < 8; ++nf) {
                const int krow = (bh << 16) + ((t0c + (nf << 4) + l15) << 6) + (quad << 3);
                const bf8v ka0 = us2bf(*(const us8v*)&Kh[krow]);
                const bf8v ka1 = us2bf(*(const us8v*)&Kh[krow + 32]);
                f4v z;
                z[0]=0.f; z[1]=0.f; z[2]=0.f; z[3]=0.f;
                z = __builtin_amdgcn_mfma_f32_16x16x32_bf16(ka0, qb0, z, 0, 0, 0);
                z = __builtin_amdgcn_mfma_f32_16x16x32_bf16(ka1, qb1, z, 0, 0, 0);
                s[nf] = z;
            }

            #pragma unroll
            for (int nf = 0; nf < 8; ++nf) {
                const us4v bm = *(const us4v*)&Bm[(bh << 20) + ((q0w + l15) << 10)
                                                 + t0c + (nf << 4) + (quad << 2)];
                #pragma unroll
                for (int r = 0; r < 4; ++r) s[nf][r] += bf2f(bm[r]);
            }

            f4v mx = s[0];
            #pragma unroll
            for (int nf = 1; nf < 8; ++nf) {
                mx[0] = fmaxf(mx[0], s[nf][0]); mx[1] = fmaxf(mx[1], s[nf][1]);
                mx[2] = fmaxf(mx[2], s[nf][2]); mx[3] = fmaxf(mx[3], s[nf][3]);
            }
            float cm = fmaxf(fmaxf(mx[0], mx[1]), fmaxf(mx[2], mx[3]));
            cm = fmaxf(cm, __shfl_xor(cm, 16));
            cm = fmaxf(cm, __shfl_xor(cm, 32));

            const float mn = fmaxf(m_run, cm);
            const float alpha = __expf(m_run - mn);
            m_run = mn;
            l_run *= alpha;
            #pragma unroll
            for (int i = 0; i < 4; ++i) {
                O[i][0] *= alpha; O[i][1] *= alpha; O[i][2] *= alpha; O[i][3] *= alpha;
            }

            float rs = 0.f;
            #pragma unroll
            for (int nf = 0; nf < 8; ++nf) {
                const float p0 = __expf(s[nf][0] - mn);
                const float p1 = __expf(s[nf][1] - mn);
                const float p2 = __expf(s[nf][2] - mn);
                const float p3 = __expf(s[nf][3] - mn);
                const int ea = l15 * 132 + (nf << 4) + (quad << 2);
                *(unsigned int*)&PsT[wv][ea] =
                    (unsigned int)f2bf(p0) | ((unsigned int)f2bf(p1) << 16);
                *(unsigned int*)&PsT[wv][ea + 2] =
                    (unsigned int)f2bf(p2) | ((unsigned int)f2bf(p3) << 16);
                rs += (p0 + p1) + (p2 + p3);
            }
            rs += __shfl_xor(rs, 16);
            rs += __shfl_xor(rs, 32);
            l_run += rs;

            #pragma unroll
            for (int tc = 0; tc < 4; ++tc) {
                const int eb = l15 * 132 + (tc << 5) + (quad << 3);
                const us4v plo = *(const us4v*)&PsT[wv][eb];
                const us4v phi = *(const us4v*)&PsT[wv][eb + 4];
                us8v pc;
                pc[0]=plo[0]; pc[1]=plo[1]; pc[2]=plo[2]; pc[3]=plo[3];
                pc[4]=phi[0]; pc[5]=phi[1]; pc[6]=phi[2]; pc[7]=phi[3];
                const bf8v pb = us2bf(pc);
                #pragma unroll
                for (int dt = 0; dt < 4; ++dt) {
                    const bf8v va = us2bf(*(const us8v*)&Vt[(bh << 16)
                        + (((dt << 4) + l15) << 10) + t0c + (tc << 5) + (quad << 3)]);
                    O[dt] = __builtin_amdgcn_mfma_f32_16x16x32_bf16(va, pb, O[dt], 0, 0, 0);
                }
            }
        }

        if (th == 1) {
            #pragma unroll
            for (int dt = 0; dt < 4; ++dt)
                *(f4v*)&OLDS[qg][l15 * 68 + (dt << 4) + (quad << 2)] = O[dt];
            if (quad == 0) { MLDS[qg][0][l15] = m_run; MLDS[qg][1][l15] = l_run; }
        }
        __syncthreads();
        if (th == 0) {
            const float m1 = MLDS[qg][0][l15];
            const float l1 = MLDS[qg][1][l15];
            const float mm = fmaxf(m_run, m1);
            const float a0 = __expf(m_run - mm);
            const float a1 = __expf(m1 - mm);
            const float linv = 1.f / (l_run * a0 + l1 * a1);
            const int orow = ((b << 10) + q0w + l15) * FF + (h << 6);
            #pragma unroll
            for (int dt = 0; dt < 4; ++dt) {
                const f4v o1 = *(const f4v*)&OLDS[qg][l15 * 68 + (dt << 4) + (quad << 2)];
                us4v ov;
                #pragma unroll
                for (int r = 0; r < 4; ++r)
                    ov[r] = f2bf((O[dt][r] * a0 + o1[r] * a1) * linv);
                *(us4v*)&aout_bf[orow + (dt << 4) + (quad << 2)] = ov;
            }
        }
        __syncthreads();                     // protect OLDS/MLDS across reps
        __asm__ volatile("" ::: "memory");
    }
}

// ---------------------------------------------------------------------------
// K5: out = aout @ Wo + bo  (MFMA, fp32 output)   [amplified xREP_OPROJ]
// ---------------------------------------------------------------------------
__global__ __launch_bounds__(256) void k_oproj(
    const unsigned short* __restrict__ aout_bf, const unsigned short* __restrict__ Wot,
    const float* __restrict__ bo, float* __restrict__ out)
{
    __shared__ __align__(16) unsigned short As[64 * 264];
    const int tid = threadIdx.x;
    const int m0 = blockIdx.x << 6;

    for (int rep = 0; rep < REP_OPROJ; ++rep) {
        #pragma unroll
        for (int u = 0; u < 8; ++u) {
            const int idx = (u << 8) + tid;
            const int r = idx >> 5, c = (idx & 31) << 3;
            *(us8v*)&As[r * 264 + c] = *(const us8v*)&aout_bf[(m0 + r) * FF + c];
        }
        __syncthreads();

        const int lane = tid & 63, nw = tid >> 6, gq = lane >> 5, l31 = lane & 31;
        f16v acc[2][2];
        #pragma unroll
        for (int i = 0; i < 2; ++i)
            #pragma unroll
            for (int j = 0; j < 2; ++j)
                #pragma unroll
                for (int e = 0; e < 16; ++e) acc[i][j][e] = 0.f;

        for (int ks = 0; ks < 16; ++ks) {
            const int k0 = (ks << 4) + (gq << 3);
            bf8v af[2], wf[2];
            af[0] = us2bf(*(const us8v*)&As[l31 * 264 + k0]);
            af[1] = us2bf(*(const us8v*)&As[(32 + l31) * 264 + k0]);
            wf[0] = us2bf(*(const us8v*)&Wot[((nw << 6) + l31) * FF + k0]);
            wf[1] = us2bf(*(const us8v*)&Wot[((nw << 6) + 32 + l31) * FF + k0]);
            #pragma unroll
            for (int ti = 0; ti < 2; ++ti)
                #pragma unroll
                for (int tj = 0; tj < 2; ++tj)
                    acc[ti][tj] = __builtin_amdgcn_mfma_f32_32x32x16_bf16(
                        af[ti], wf[tj], acc[ti][tj], 0, 0, 0);
        }

        #pragma unroll
        for (int ti = 0; ti < 2; ++ti)
            #pragma unroll
            for (int tj = 0; tj < 2; ++tj)
                #pragma unroll
                for (int reg = 0; reg < 16; ++reg) {
                    const int row = (reg & 3) + ((reg >> 2) << 3) + (gq << 2);
                    const int tg = m0 + (ti << 5) + row;
                    const int n = (nw << 6) + (tj << 5) + l31;
                    out[tg * FF + n] = acc[ti][tj][reg] + bo[n];
                }
        __syncthreads();                     // protect As across reps
        __asm__ volatile("" ::: "memory");
    }
}

// ---------------------------------------------------------------------------
// ws layout (MB): Wt 0..0.5 | qin_bf @1 | xn_bf @5 | Qh @9 | Kh @13 |
// Vt @17 | aout_bf @21 | Bm (full 32x1024x1024 bf16 = 64MB) @25..89.
// ---------------------------------------------------------------------------
extern "C" void kernel_launch(void* const* d_in, const int* in_sizes, int n_in,
                              void* d_out, int out_size, void* d_ws, size_t ws_size,
                              hipStream_t stream)
{
    const float* x    = (const float*)d_in[0];
    const float* qin  = (const float*)d_in[1];
    const float* posk = (const float*)d_in[2];
    const int*   mask = (const int*)d_in[3];
    const float* ln_g = (const float*)d_in[4];
    const float* ln_b = (const float*)d_in[5];
    const float* Wq   = (const float*)d_in[6];
    const float* bq   = (const float*)d_in[7];
    const float* Wk   = (const float*)d_in[8];
    const float* bk   = (const float*)d_in[9];
    const float* Wv   = (const float*)d_in[10];
    const float* bv   = (const float*)d_in[11];
    const float* Wo   = (const float*)d_in[12];
    const float* bo   = (const float*)d_in[13];
    float* out = (float*)d_out;

    char* ws = (char*)d_ws;
    unsigned short* wWt   = (unsigned short*)(ws);
    unsigned short* qinb  = (unsigned short*)(ws + (size_t)(1u << 20));
    unsigned short* xnb   = (unsigned short*)(ws + (size_t)(5u << 20));
    unsigned short* Qh    = (unsigned short*)(ws + (size_t)(9u << 20));
    unsigned short* Kh    = (unsigned short*)(ws + (size_t)(13u << 20));
    unsigned short* Vth   = (unsigned short*)(ws + (size_t)(17u << 20));
    unsigned short* aoutb = (unsigned short*)(ws + (size_t)(21u << 20));
    unsigned short* Bm    = (unsigned short*)(ws + (size_t)(25u << 20));

    hipLaunchKernelGGL(k_wprep, dim3(64, 4), dim3(256), 0, stream, Wq, Wk, Wv, Wo, wWt);
    hipLaunchKernelGGL(k_ln, dim3(512), dim3(256), 0, stream,
                       x, qin, ln_g, ln_b, xnb, qinb);
    hipLaunchKernelGGL(k_proj, dim3(128, 3), dim3(256), 0, stream,
                       qinb, xnb, wWt, bq, bk, bv, Qh, Kh, Vth);
    hipLaunchKernelGGL(k_bterm, dim3(8, 1024), dim3(256), 0, stream,
                       Qh, posk, mask, Bm);
    hipLaunchKernelGGL(k_attn, dim3(1024), dim3(256), 0, stream,
                       Qh, Kh, Vth, Bm, aoutb);
    hipLaunchKernelGGL(k_oproj, dim3(128), dim3(256), 0, stream,
                       aoutb, wWt + (3 << 16), bo, out);
}

// Round 6
// 526.330 us; speedup vs baseline: 2.5799x; 2.5799x over previous
//
#include <hip/hip_runtime.h>
#include <hip/hip_bf16.h>

#define TT 1024
#define FF 256

typedef float  f4v  __attribute__((ext_vector_type(4)));
typedef float  f16v __attribute__((ext_vector_type(16)));
typedef __bf16 bf8v __attribute__((ext_vector_type(8)));
typedef unsigned short us8v __attribute__((ext_vector_type(8)));
typedef unsigned short us4v __attribute__((ext_vector_type(4)));

static __device__ __forceinline__ unsigned short f2bf(float x) {
    return __builtin_bit_cast(unsigned short, (__bf16)x);
}
static __device__ __forceinline__ float bf2f(unsigned short u) {
    return (float)__builtin_bit_cast(__bf16, u);
}
static __device__ __forceinline__ bf8v us2bf(us8v v) {
    return __builtin_bit_cast(bf8v, v);
}

// ---------------------------------------------------------------------------
// K0: weight prep — W[k][n] fp32 -> Wt[n][k] bf16, 4 matrices (Q,K,V,O).
// ---------------------------------------------------------------------------
__global__ __launch_bounds__(256) void k_wprep(
    const float* __restrict__ Wq, const float* __restrict__ Wk,
    const float* __restrict__ Wv, const float* __restrict__ Wo,
    unsigned short* __restrict__ Wt)
{
    __shared__ unsigned short T[32][36];
    const float* W = (blockIdx.y == 0) ? Wq : (blockIdx.y == 1) ? Wk
                   : (blockIdx.y == 2) ? Wv : Wo;
    unsigned short* dst = Wt + (blockIdx.y << 16);
    const int kt = (blockIdx.x >> 3) << 5, nt = (blockIdx.x & 7) << 5;
    const int r = threadIdx.x >> 3, c0 = (threadIdx.x & 7) << 2;
    const f4v w = *(const f4v*)&W[(kt + r) * FF + nt + c0];
    #pragma unroll
    for (int j = 0; j < 4; ++j) T[c0 + j][r] = f2bf(w[j]);
    __syncthreads();
    *(us4v*)&dst[(nt + r) * FF + kt + c0] = *(const us4v*)&T[r][c0];
}

// ---------------------------------------------------------------------------
// K1: LayerNorm(x) -> xn_bf16 ; cast q_in -> bf16.
// ---------------------------------------------------------------------------
__global__ __launch_bounds__(256) void k_ln(
    const float* __restrict__ x, const float* __restrict__ qin,
    const float* __restrict__ lng, const float* __restrict__ lnb,
    unsigned short* __restrict__ xn_bf, unsigned short* __restrict__ qin_bf)
{
    const int tid = threadIdx.x, lane = tid & 63, wv = tid >> 6;
    const int r0 = blockIdx.x << 4;

    #pragma unroll
    for (int u = 0; u < 4; ++u) {
        const int i4 = ((u << 8) + tid) << 2;
        const int r = i4 >> 8, c = i4 & 255;
        const f4v qv = *(const f4v*)&qin[(r0 + r) * FF + c];
        us4v o;
        #pragma unroll
        for (int j = 0; j < 4; ++j) o[j] = f2bf(qv[j]);
        *(us4v*)&qin_bf[(r0 + r) * FF + c] = o;
    }

    #pragma unroll
    for (int rr = 0; rr < 4; ++rr) {
        const int row = r0 + (wv << 2) + rr;
        float v[4], s = 0.f, s2 = 0.f;
        #pragma unroll
        for (int c4 = 0; c4 < 4; ++c4) {
            v[c4] = x[row * FF + (c4 << 6) + lane];
            s += v[c4]; s2 += v[c4] * v[c4];
        }
        #pragma unroll
        for (int off = 1; off < 64; off <<= 1) {
            s  += __shfl_xor(s, off);
            s2 += __shfl_xor(s2, off);
        }
        const float mu  = s * (1.f / FF);
        const float rsd = rsqrtf(s2 * (1.f / FF) - mu * mu + 1e-5f);
        #pragma unroll
        for (int c4 = 0; c4 < 4; ++c4) {
            const int c = (c4 << 6) + lane;
            xn_bf[row * FF + c] = f2bf((v[c4] - mu) * rsd * lng[c] + lnb[c]);
        }
    }
}

// ---------------------------------------------------------------------------
// K2: MFMA projections.  z=0: Qh = (qin@Wq + bq)*0.125; z=1: Kh = xn@Wk + bk;
// z=2: Vt = (xn@Wv + bv)^T stored [bh][d][t].
// ---------------------------------------------------------------------------
__global__ __launch_bounds__(256) void k_proj(
    const unsigned short* __restrict__ qin_bf, const unsigned short* __restrict__ xn_bf,
    const unsigned short* __restrict__ Wt,
    const float* __restrict__ bq, const float* __restrict__ bk, const float* __restrict__ bv,
    unsigned short* __restrict__ Qh, unsigned short* __restrict__ Kh,
    unsigned short* __restrict__ Vt)
{
    __shared__ __align__(16) unsigned short As[64 * 264];
    const int z = blockIdx.y;
    const unsigned short* A = (z == 0) ? qin_bf : xn_bf;
    const unsigned short* W = Wt + (z << 16);
    const float* bias = (z == 0) ? bq : (z == 1) ? bk : bv;
    unsigned short* dst = (z == 0) ? Qh : (z == 1) ? Kh : Vt;
    const int tid = threadIdx.x;
    const int m0 = blockIdx.x << 6;

    #pragma unroll
    for (int u = 0; u < 8; ++u) {
        const int idx = (u << 8) + tid;
        const int r = idx >> 5, c = (idx & 31) << 3;
        *(us8v*)&As[r * 264 + c] = *(const us8v*)&A[(m0 + r) * FF + c];
    }
    __syncthreads();

    const int lane = tid & 63, nw = tid >> 6, gq = lane >> 5, l31 = lane & 31;
    f16v acc[2][2];
    #pragma unroll
    for (int i = 0; i < 2; ++i)
        #pragma unroll
        for (int j = 0; j < 2; ++j)
            #pragma unroll
            for (int e = 0; e < 16; ++e) acc[i][j][e] = 0.f;

    for (int ks = 0; ks < 16; ++ks) {
        const int k0 = (ks << 4) + (gq << 3);
        bf8v af[2], wf[2];
        af[0] = us2bf(*(const us8v*)&As[l31 * 264 + k0]);
        af[1] = us2bf(*(const us8v*)&As[(32 + l31) * 264 + k0]);
        wf[0] = us2bf(*(const us8v*)&W[((nw << 6) + l31) * FF + k0]);
        wf[1] = us2bf(*(const us8v*)&W[((nw << 6) + 32 + l31) * FF + k0]);
        if (z == 2) {
            #pragma unroll
            for (int ti = 0; ti < 2; ++ti)
                #pragma unroll
                for (int tj = 0; tj < 2; ++tj)
                    acc[ti][tj] = __builtin_amdgcn_mfma_f32_32x32x16_bf16(
                        wf[tj], af[ti], acc[ti][tj], 0, 0, 0);
        } else {
            #pragma unroll
            for (int ti = 0; ti < 2; ++ti)
                #pragma unroll
                for (int tj = 0; tj < 2; ++tj)
                    acc[ti][tj] = __builtin_amdgcn_mfma_f32_32x32x16_bf16(
                        af[ti], wf[tj], acc[ti][tj], 0, 0, 0);
        }
    }

    if (z != 2) {
        #pragma unroll
        for (int ti = 0; ti < 2; ++ti)
            #pragma unroll
            for (int tj = 0; tj < 2; ++tj)
                #pragma unroll
                for (int reg = 0; reg < 16; ++reg) {
                    const int row = (reg & 3) + ((reg >> 2) << 3) + (gq << 2);
                    const int tg = m0 + (ti << 5) + row;
                    const int n = (nw << 6) + (tj << 5) + l31;
                    float val = acc[ti][tj][reg] + bias[n];
                    if (z == 0) val *= 0.125f;
                    const int b = tg >> 10, t = tg & 1023;
                    dst[(((b << 2) + nw) << 16) + (t << 6) + (tj << 5) + l31] = f2bf(val);
                }
    } else {
        #pragma unroll
        for (int ti = 0; ti < 2; ++ti)
            #pragma unroll
            for (int tj = 0; tj < 2; ++tj)
                #pragma unroll
                for (int reg = 0; reg < 16; ++reg) {
                    const int row = (reg & 3) + ((reg >> 2) << 3) + (gq << 2);
                    const int d = (tj << 5) + row;
                    const int tg = m0 + (ti << 5) + l31;
                    const float val = acc[ti][tj][reg] + bias[(nw << 6) + d];
                    const int b = tg >> 10, t = tg & 1023;
                    dst[(((b << 2) + nw) << 16) + (d << 10) + t] = f2bf(val);
                }
    }
}

// ---------------------------------------------------------------------------
// K3: relative-position term with mask+scale folded (unchanged).
// Bm[bh][q][t] = mask ? Qh_scaled[bh][q].posk[q][t] : -3e38  (bf16)
// ---------------------------------------------------------------------------
__global__ __launch_bounds__(256) void k_bterm(
    const unsigned short* __restrict__ Qh, const float* __restrict__ posk,
    const int* __restrict__ mask, unsigned short* __restrict__ Bm)
{
    const int tid = threadIdx.x, lane = tid & 63, wv = tid >> 6;
    const int gq = lane >> 5, m = lane & 31;
    const int q = blockIdx.y;
    const int t = (blockIdx.x << 7) + (wv << 5) + m;

    bf8v afr[4];
    #pragma unroll
    for (int kk = 0; kk < 4; ++kk)
        afr[kk] = us2bf(*(const us8v*)&Qh[(m << 16) + (q << 6) + (kk << 4) + (gq << 3)]);

    bf8v bfr[4];
    #pragma unroll
    for (int kk = 0; kk < 4; ++kk) {
        const int d0 = (kk << 4) + (gq << 3);
        const f4v p0 = *(const f4v*)&posk[(((q << 10) + t) << 6) + d0];
        const f4v p1 = *(const f4v*)&posk[(((q << 10) + t) << 6) + d0 + 4];
        bf8v bb;
        bb[0] = (__bf16)p0[0]; bb[1] = (__bf16)p0[1];
        bb[2] = (__bf16)p0[2]; bb[3] = (__bf16)p0[3];
        bb[4] = (__bf16)p1[0]; bb[5] = (__bf16)p1[1];
        bb[6] = (__bf16)p1[2]; bb[7] = (__bf16)p1[3];
        bfr[kk] = bb;
    }

    f16v acc;
    #pragma unroll
    for (int i = 0; i < 16; ++i) acc[i] = 0.f;
    #pragma unroll
    for (int kk = 0; kk < 4; ++kk)
        acc = __builtin_amdgcn_mfma_f32_32x32x16_bf16(afr[kk], bfr[kk], acc, 0, 0, 0);

    int mk[4];
    #pragma unroll
    for (int g = 0; g < 4; ++g)   // b = 2g + gq for reg group g
        mk[g] = mask[(((g << 1) + gq) << 20) + (q << 10) + t];
    #pragma unroll
    for (int reg = 0; reg < 16; ++reg) {
        const int g = reg >> 2;
        const int bhr = (reg & 3) + (g << 3) + (gq << 2);
        const float val = mk[g] ? acc[reg] : -3.0e38f;
        Bm[(bhr << 20) + (q << 10) + t] = f2bf(val);
    }
}

// ---------------------------------------------------------------------------
// K4 (R5): transposed flash attention, latency-optimized.
// R4's counters (amplified): MfmaUtil 4.7%, VALUBusy 13%, VGPR=56 -> the
// compiler serialized all global loads (load->wait->use), ~15 L3 round trips
// per chunk.  Fix: batch all V loads up-front per chunk; prefetch next
// chunk's K+Bm right after QK consumes the current ones; __launch_bounds__
// (256,2) gives the allocator 256 VGPRs so ~40 loads stay in flight.
// sched_barrier(0) fences keep the scheduler from re-sinking the batches.
// ---------------------------------------------------------------------------
__global__ __launch_bounds__(256, 2) void k_attn(
    const unsigned short* __restrict__ Qh, const unsigned short* __restrict__ Kh,
    const unsigned short* __restrict__ Vt, const unsigned short* __restrict__ Bm,
    unsigned short* __restrict__ aout_bf)
{
    __shared__ __align__(16) unsigned short PsT[4][16 * 132]; // per-wave [q][t]
    __shared__ __align__(16) float OLDS[2][16 * 68];          // [qg][q][d]
    __shared__ float MLDS[2][2][16];                          // [qg][{m,l}][q]

    const int tid = threadIdx.x, lane = tid & 63, wv = tid >> 6;
    const int l15 = lane & 15, quad = lane >> 4;
    const int qg = wv & 1, th = wv >> 1;
    const int blk = blockIdx.x;
    const int bh = ((blk & 7) << 2) | ((blk >> 3) & 3);  // XCD swizzle
    const int qt = blk >> 5;
    const int b = bh >> 2, h = bh & 3;
    const int q0w = (qt << 5) + (qg << 4);               // wave's 16 q rows

    const unsigned short* Kbase = Kh + (bh << 16);
    const unsigned short* Vbase = Vt + (bh << 16);
    const unsigned short* Bbase = Bm + (bh << 20) + ((q0w + l15) << 10);

    // Q B-fragments (B[k=d][n=q], n = l15): loaded once
    bf8v qb0, qb1;
    {
        const int base = (bh << 16) + ((q0w + l15) << 6) + (quad << 3);
        qb0 = us2bf(*(const us8v*)&Qh[base]);
        qb1 = us2bf(*(const us8v*)&Qh[base + 32]);
    }

    f4v O[4];
    #pragma unroll
    for (int i = 0; i < 4; ++i) { O[i][0]=0.f; O[i][1]=0.f; O[i][2]=0.f; O[i][3]=0.f; }
    float m_run = -3.0e38f, l_run = 0.f;

    // ---- prologue: batch-issue chunk 0's K + Bm loads ----
    us8v kreg[8][2];
    us4v bmreg[8];
    {
        const int t0c = th << 9;
        #pragma unroll
        for (int nf = 0; nf < 8; ++nf) {
            const int krow = ((t0c + (nf << 4) + l15) << 6) + (quad << 3);
            kreg[nf][0] = *(const us8v*)&Kbase[krow];
            kreg[nf][1] = *(const us8v*)&Kbase[krow + 32];
        }
        #pragma unroll
        for (int nf = 0; nf < 8; ++nf)
            bmreg[nf] = *(const us4v*)&Bbase[t0c + (nf << 4) + (quad << 2)];
    }

    for (int cc = 0; cc < 4; ++cc) {
        const int t0c = (th << 9) + (cc << 7);

        // ---- batch-issue this chunk's 16 V loads (consumed at PV) ----
        us8v vreg[4][4];
        #pragma unroll
        for (int tc = 0; tc < 4; ++tc)
            #pragma unroll
            for (int dt = 0; dt < 4; ++dt)
                vreg[tc][dt] = *(const us8v*)&Vbase[(((dt << 4) + l15) << 10)
                                                   + t0c + (tc << 5) + (quad << 3)];
        __builtin_amdgcn_sched_barrier(0);   // keep V batch issued here

        // ---- S^T = K Q^T (consumes kreg) + Bm add ----
        f4v s[8];
        #pragma unroll
        for (int nf = 0; nf < 8; ++nf) {
            f4v z;
            z[0]=0.f; z[1]=0.f; z[2]=0.f; z[3]=0.f;
            z = __builtin_amdgcn_mfma_f32_16x16x32_bf16(us2bf(kreg[nf][0]), qb0, z, 0, 0, 0);
            z = __builtin_amdgcn_mfma_f32_16x16x32_bf16(us2bf(kreg[nf][1]), qb1, z, 0, 0, 0);
            #pragma unroll
            for (int r = 0; r < 4; ++r) z[r] += bf2f(bmreg[nf][r]);
            s[nf] = z;
        }

        // ---- prefetch next chunk's K + Bm (kreg/bmreg now dead) ----
        if (cc < 3) {
            const int t0n = (th << 9) + ((cc + 1) << 7);
            #pragma unroll
            for (int nf = 0; nf < 8; ++nf) {
                const int krow = ((t0n + (nf << 4) + l15) << 6) + (quad << 3);
                kreg[nf][0] = *(const us8v*)&Kbase[krow];
                kreg[nf][1] = *(const us8v*)&Kbase[krow + 32];
            }
            #pragma unroll
            for (int nf = 0; nf < 8; ++nf)
                bmreg[nf] = *(const us4v*)&Bbase[t0n + (nf << 4) + (quad << 2)];
        }
        __builtin_amdgcn_sched_barrier(0);   // keep prefetch issued here

        // ---- chunk max for column q = l15: in-register + 2 shuffles ----
        f4v mx = s[0];
        #pragma unroll
        for (int nf = 1; nf < 8; ++nf) {
            mx[0] = fmaxf(mx[0], s[nf][0]); mx[1] = fmaxf(mx[1], s[nf][1]);
            mx[2] = fmaxf(mx[2], s[nf][2]); mx[3] = fmaxf(mx[3], s[nf][3]);
        }
        float cm = fmaxf(fmaxf(mx[0], mx[1]), fmaxf(mx[2], mx[3]));
        cm = fmaxf(cm, __shfl_xor(cm, 16));
        cm = fmaxf(cm, __shfl_xor(cm, 32));

        const float mn = fmaxf(m_run, cm);
        const float alpha = __expf(m_run - mn);
        m_run = mn;
        l_run *= alpha;
        #pragma unroll
        for (int i = 0; i < 4; ++i) {
            O[i][0] *= alpha; O[i][1] *= alpha; O[i][2] *= alpha; O[i][3] *= alpha;
        }

        // ---- exp, write P^T to wave-private LDS [q][t], row-sum ----
        float rs = 0.f;
        #pragma unroll
        for (int nf = 0; nf < 8; ++nf) {
            const float p0 = __expf(s[nf][0] - mn);
            const float p1 = __expf(s[nf][1] - mn);
            const float p2 = __expf(s[nf][2] - mn);
            const float p3 = __expf(s[nf][3] - mn);
            const int ea = l15 * 132 + (nf << 4) + (quad << 2);
            *(unsigned int*)&PsT[wv][ea] =
                (unsigned int)f2bf(p0) | ((unsigned int)f2bf(p1) << 16);
            *(unsigned int*)&PsT[wv][ea + 2] =
                (unsigned int)f2bf(p2) | ((unsigned int)f2bf(p3) << 16);
            rs += (p0 + p1) + (p2 + p3);
        }
        rs += __shfl_xor(rs, 16);
        rs += __shfl_xor(rs, 32);
        l_run += rs;

        // ---- PV: O^T[d][q] += V^T P^T (V from vreg, P from PsT) ----
        #pragma unroll
        for (int tc = 0; tc < 4; ++tc) {
            const int eb = l15 * 132 + (tc << 5) + (quad << 3);
            const us4v plo = *(const us4v*)&PsT[wv][eb];
            const us4v phi = *(const us4v*)&PsT[wv][eb + 4];
            us8v pc;
            pc[0]=plo[0]; pc[1]=plo[1]; pc[2]=plo[2]; pc[3]=plo[3];
            pc[4]=phi[0]; pc[5]=phi[1]; pc[6]=phi[2]; pc[7]=phi[3];
            const bf8v pb = us2bf(pc);
            #pragma unroll
            for (int dt = 0; dt < 4; ++dt)
                O[dt] = __builtin_amdgcn_mfma_f32_16x16x32_bf16(
                    us2bf(vreg[tc][dt]), pb, O[dt], 0, 0, 0);
        }
    }

    // ---- merge the two t-halves (one barrier) ----
    if (th == 1) {
        #pragma unroll
        for (int dt = 0; dt < 4; ++dt)
            *(f4v*)&OLDS[qg][l15 * 68 + (dt << 4) + (quad << 2)] = O[dt];
        if (quad == 0) { MLDS[qg][0][l15] = m_run; MLDS[qg][1][l15] = l_run; }
    }
    __syncthreads();
    if (th == 0) {
        const float m1 = MLDS[qg][0][l15];
        const float l1 = MLDS[qg][1][l15];
        const float mm = fmaxf(m_run, m1);
        const float a0 = __expf(m_run - mm);
        const float a1 = __expf(m1 - mm);
        const float linv = 1.f / (l_run * a0 + l1 * a1);
        const int orow = ((b << 10) + q0w + l15) * FF + (h << 6);
        #pragma unroll
        for (int dt = 0; dt < 4; ++dt) {
            const f4v o1 = *(const f4v*)&OLDS[qg][l15 * 68 + (dt << 4) + (quad << 2)];
            us4v ov;
            #pragma unroll
            for (int r = 0; r < 4; ++r)
                ov[r] = f2bf((O[dt][r] * a0 + o1[r] * a1) * linv);
            *(us4v*)&aout_bf[orow + (dt << 4) + (quad << 2)] = ov;
        }
    }
}

// ---------------------------------------------------------------------------
// K5: out = aout @ Wo + bo  (MFMA, fp32 output)
// ---------------------------------------------------------------------------
__global__ __launch_bounds__(256) void k_oproj(
    const unsigned short* __restrict__ aout_bf, const unsigned short* __restrict__ Wot,
    const float* __restrict__ bo, float* __restrict__ out)
{
    __shared__ __align__(16) unsigned short As[64 * 264];
    const int tid = threadIdx.x;
    const int m0 = blockIdx.x << 6;

    #pragma unroll
    for (int u = 0; u < 8; ++u) {
        const int idx = (u << 8) + tid;
        const int r = idx >> 5, c = (idx & 31) << 3;
        *(us8v*)&As[r * 264 + c] = *(const us8v*)&aout_bf[(m0 + r) * FF + c];
    }
    __syncthreads();

    const int lane = tid & 63, nw = tid >> 6, gq = lane >> 5, l31 = lane & 31;
    f16v acc[2][2];
    #pragma unroll
    for (int i = 0; i < 2; ++i)
        #pragma unroll
        for (int j = 0; j < 2; ++j)
            #pragma unroll
            for (int e = 0; e < 16; ++e) acc[i][j][e] = 0.f;

    for (int ks = 0; ks < 16; ++ks) {
        const int k0 = (ks << 4) + (gq << 3);
        bf8v af[2], wf[2];
        af[0] = us2bf(*(const us8v*)&As[l31 * 264 + k0]);
        af[1] = us2bf(*(const us8v*)&As[(32 + l31) * 264 + k0]);
        wf[0] = us2bf(*(const us8v*)&Wot[((nw << 6) + l31) * FF + k0]);
        wf[1] = us2bf(*(const us8v*)&Wot[((nw << 6) + 32 + l31) * FF + k0]);
        #pragma unroll
        for (int ti = 0; ti < 2; ++ti)
            #pragma unroll
            for (int tj = 0; tj < 2; ++tj)
                acc[ti][tj] = __builtin_amdgcn_mfma_f32_32x32x16_bf16(
                    af[ti], wf[tj], acc[ti][tj], 0, 0, 0);
    }

    #pragma unroll
    for (int ti = 0; ti < 2; ++ti)
        #pragma unroll
        for (int tj = 0; tj < 2; ++tj)
            #pragma unroll
            for (int reg = 0; reg < 16; ++reg) {
                const int row = (reg & 3) + ((reg >> 2) << 3) + (gq << 2);
                const int tg = m0 + (ti << 5) + row;
                const int n = (nw << 6) + (tj << 5) + l31;
                out[tg * FF + n] = acc[ti][tj][reg] + bo[n];
            }
}

// ---------------------------------------------------------------------------
// ws layout (MB): Wt 0..0.5 | qin_bf @1 | xn_bf @5 | Qh @9 | Kh @13 |
// Vt @17 | aout_bf @21 | Bm (full 32x1024x1024 bf16 = 64MB) @25..89.
// ---------------------------------------------------------------------------
extern "C" void kernel_launch(void* const* d_in, const int* in_sizes, int n_in,
                              void* d_out, int out_size, void* d_ws, size_t ws_size,
                              hipStream_t stream)
{
    const float* x    = (const float*)d_in[0];
    const float* qin  = (const float*)d_in[1];
    const float* posk = (const float*)d_in[2];
    const int*   mask = (const int*)d_in[3];
    const float* ln_g = (const float*)d_in[4];
    const float* ln_b = (const float*)d_in[5];
    const float* Wq   = (const float*)d_in[6];
    const float* bq   = (const float*)d_in[7];
    const float* Wk   = (const float*)d_in[8];
    const float* bk   = (const float*)d_in[9];
    const float* Wv   = (const float*)d_in[10];
    const float* bv   = (const float*)d_in[11];
    const float* Wo   = (const float*)d_in[12];
    const float* bo   = (const float*)d_in[13];
    float* out = (float*)d_out;

    char* ws = (char*)d_ws;
    unsigned short* wWt   = (unsigned short*)(ws);
    unsigned short* qinb  = (unsigned short*)(ws + (size_t)(1u << 20));
    unsigned short* xnb   = (unsigned short*)(ws + (size_t)(5u << 20));
    unsigned short* Qh    = (unsigned short*)(ws + (size_t)(9u << 20));
    unsigned short* Kh    = (unsigned short*)(ws + (size_t)(13u << 20));
    unsigned short* Vth   = (unsigned short*)(ws + (size_t)(17u << 20));
    unsigned short* aoutb = (unsigned short*)(ws + (size_t)(21u << 20));
    unsigned short* Bm    = (unsigned short*)(ws + (size_t)(25u << 20));

    hipLaunchKernelGGL(k_wprep, dim3(64, 4), dim3(256), 0, stream, Wq, Wk, Wv, Wo, wWt);
    hipLaunchKernelGGL(k_ln, dim3(512), dim3(256), 0, stream,
                       x, qin, ln_g, ln_b, xnb, qinb);
    hipLaunchKernelGGL(k_proj, dim3(128, 3), dim3(256), 0, stream,
                       qinb, xnb, wWt, bq, bk, bv, Qh, Kh, Vth);
    hipLaunchKernelGGL(k_bterm, dim3(8, 1024), dim3(256), 0, stream,
                       Qh, posk, mask, Bm);
    hipLaunchKernelGGL(k_attn, dim3(1024), dim3(256), 0, stream,
                       Qh, Kh, Vth, Bm, aoutb);
    hipLaunchKernelGGL(k_oproj, dim3(128), dim3(256), 0, stream,
                       aoutb, wWt + (3 << 16), bo, out);
}